// Round 6
// baseline (1596.206 us; speedup 1.0000x reference)
//
#include <hip/hip_runtime.h>

// Problem constants
#define BATCH 32
#define CDIM 256
#define HW 4096            // 64*64
#define NVEC 131072        // BATCH*HW
#define NE 1024
#define DECAY 0.99f
#define ONE_MINUS_DECAY 0.01f
#define EPSV 1e-5f
#define ZQ_ELEMS 33554432  // BATCH*CDIM*HW
#define MARGIN 0.02f       // f16-split worst-case distance error ~0.003; 6x safety

typedef _Float16 half8 __attribute__((ext_vector_type(8)));
typedef _Float16 half4 __attribute__((ext_vector_type(4)));
typedef float    f32x4 __attribute__((ext_vector_type(4)));

// ---------------- K0: emb fp32 -> f16 hi/lo split arrays [1024,256] ----------------
__global__ __launch_bounds__(256) void prep_half_kernel(
    const float* __restrict__ emb, _Float16* __restrict__ embH,
    _Float16* __restrict__ embL) {
  int i = blockIdx.x * 256 + threadIdx.x;   // 65536 float4 chunks
  float4 v = ((const float4*)emb)[i];
  float x[4] = {v.x, v.y, v.z, v.w};
  half4 hv, lv;
  #pragma unroll
  for (int j = 0; j < 4; ++j) {
    _Float16 h = (_Float16)x[j];
    hv[j] = h;
    lv[j] = (_Float16)(x[j] - (float)h);
  }
  *(half4*)(embH + 4 * (size_t)i) = hv;
  *(half4*)(embL + 4 * (size_t)i) = lv;
}

// ---------------- K1: embedding row squared norms (fp32, exact) ----------------
__global__ __launch_bounds__(256) void enorm_kernel(
    const float* __restrict__ emb, float* __restrict__ enorm) {
  int gid  = blockIdx.x * 256 + threadIdx.x;
  int e    = gid >> 6;
  int lane = threadIdx.x & 63;
  const float4* row = (const float4*)(emb + ((size_t)e << 8));
  float4 v = row[lane];
  float s = v.x * v.x + v.y * v.y + v.z * v.z + v.w * v.w;
  #pragma unroll
  for (int off = 32; off > 0; off >>= 1) s += __shfl_down(s, off);
  if (lane == 0) enorm[e] = s;
}

// ---------------- K2: MFMA argmin — 3-term f16 split GEMM + argmin epilogue ----------
// Block: 64 n-rows, 512 thr = 8 waves (2 n-halves x 4 e-strips), wave tile
// 32n x 64e, 4 e-passes (E=1024). A (z hi/lo f16) staged once in LDS,
// XOR-swizzled; B (embH/embL) read from global (L2-resident, 1MB) directly
// into fragments -> K-loop has NO barriers.
// Occupancy fix vs r5 (VGPR=256 -> 1-2 waves/SIMD, latency-bound): halved
// wave tile needs ~90 live regs; launch_bounds(512,4) caps VGPR at 128 ->
// 4 waves/SIMD; LDS 64KB -> 2 blocks/CU x 8 waves = 16 waves/CU (50%).
__global__ __launch_bounds__(512, 4) void argmin_kernel(
    const float* __restrict__ z, const _Float16* __restrict__ embH,
    const _Float16* __restrict__ embL, const float* __restrict__ enorm,
    int* __restrict__ idx_ws, float* __restrict__ idx_out,
    float* __restrict__ counts, int* __restrict__ flag_cnt,
    int* __restrict__ flag_list) {
  // zh [64][256] f16 (32KB) + zl (32KB); 16B slots XOR-swizzled by (row&31)
  __shared__ char smem[65536];

  const int t = threadIdx.x;
  const int w = t >> 6;        // wave 0..7
  const int l = t & 63;
  const int g = l >> 4;        // 0..3: k-group (A/B), row-group (D)
  const int c = l & 15;        // 0..15: A row / B,D col
  const int wn = w >> 2;       // n-half: rows 32*wn .. 32*wn+31
  const int we = w & 3;        // e-strip

  const int n0  = blockIdx.x * 64;
  const int b   = n0 >> 12;
  const int hw0 = n0 & 4095;
  const float* zb = z + ((size_t)b << 20) + hw0;

  // ---- stage A once: z[64n][256k] -> f16 hi/lo, swizzled slots ----
  {
    const int n  = t & 63;
    const int kg = t >> 6;     // 0..7
    char* zhp = smem;
    char* zlp = smem + 32768;
    #pragma unroll
    for (int it = 0; it < 4; ++it) {
      const int k0 = it * 64 + kg * 8;
      half8 hv, lv;
      #pragma unroll
      for (int j = 0; j < 8; ++j) {
        float x = zb[(size_t)(k0 + j) * HW + n];   // coalesced across lanes (n)
        _Float16 h = (_Float16)x;
        hv[j] = h;
        lv[j] = (_Float16)(x - (float)h);
      }
      const int slot = ((k0 >> 3) ^ (n & 31)) & 31;
      const int byte = n * 512 + slot * 16;
      *(half8*)(zhp + byte) = hv;
      *(half8*)(zlp + byte) = lv;
    }
  }
  __syncthreads();

  // per-lane running best over the 8 n-rows this lane owns:
  // n = 32*wn + 16*mi + 4*g + r
  // amb: bit (mi*4+r) set <=> some e within MARGIN of current best for that row
  float bd[2][4];
  int   bi[2][4];
  unsigned amb = 0u;
  #pragma unroll
  for (int mi = 0; mi < 2; ++mi)
    #pragma unroll
    for (int r = 0; r < 4; ++r) { bd[mi][r] = 3.0e38f; bi[mi][r] = 0; }

  int arow[2], axor[2];
  #pragma unroll
  for (int mi = 0; mi < 2; ++mi) {
    int rowm = 32 * wn + 16 * mi + c;  // A row this lane supplies
    arow[mi] = rowm * 512;
    axor[mi] = rowm & 31;
  }

  const char* bhp = (const char*)embH;
  const char* blp = (const char*)embL;

  #pragma unroll 1
  for (int et = 0; et < 4; ++et) {
    const int ebase = et * 256 + we * 64;
    f32x4 acc[2][4];
    #pragma unroll
    for (int mi = 0; mi < 2; ++mi)
      #pragma unroll
      for (int ni = 0; ni < 4; ++ni) {
        f32x4 zr = {0.0f, 0.0f, 0.0f, 0.0f};
        acc[mi][ni] = zr;
      }

    int boff[4];
    #pragma unroll
    for (int ni = 0; ni < 4; ++ni) {
      int eg = ebase + 16 * ni + c;              // B col (e) this lane supplies
      boff[ni] = eg * 512 + g * 16;
    }

    // barrier-free K loop; B-frags in 2 ni-halves to cap register pressure
    #pragma unroll
    for (int kc = 0; kc < 256; kc += 32) {
      half8 ah[2], al[2];
      const int kslot = (kc >> 3) + g;
      #pragma unroll
      for (int mi = 0; mi < 2; ++mi) {
        int byte = arow[mi] + (((kslot ^ axor[mi]) & 31) << 4);
        ah[mi] = *(const half8*)(smem + byte);
        al[mi] = *(const half8*)(smem + 32768 + byte);
      }
      #pragma unroll
      for (int nh = 0; nh < 2; ++nh) {
        half8 bh0, bl0, bh1, bl1;
        {
          int o0 = boff[2 * nh]     + kc * 2;
          int o1 = boff[2 * nh + 1] + kc * 2;
          bh0 = *(const half8*)(bhp + o0);
          bl0 = *(const half8*)(blp + o0);
          bh1 = *(const half8*)(bhp + o1);
          bl1 = *(const half8*)(blp + o1);
        }
        #pragma unroll
        for (int mi = 0; mi < 2; ++mi) {
          acc[mi][2*nh]   = __builtin_amdgcn_mfma_f32_16x16x32_f16(ah[mi], bh0, acc[mi][2*nh],   0, 0, 0);
          acc[mi][2*nh]   = __builtin_amdgcn_mfma_f32_16x16x32_f16(ah[mi], bl0, acc[mi][2*nh],   0, 0, 0);
          acc[mi][2*nh]   = __builtin_amdgcn_mfma_f32_16x16x32_f16(al[mi], bh0, acc[mi][2*nh],   0, 0, 0);
          acc[mi][2*nh+1] = __builtin_amdgcn_mfma_f32_16x16x32_f16(ah[mi], bh1, acc[mi][2*nh+1], 0, 0, 0);
          acc[mi][2*nh+1] = __builtin_amdgcn_mfma_f32_16x16x32_f16(ah[mi], bl1, acc[mi][2*nh+1], 0, 0, 0);
          acc[mi][2*nh+1] = __builtin_amdgcn_mfma_f32_16x16x32_f16(al[mi], bh1, acc[mi][2*nh+1], 0, 0, 0);
        }
      }
    }

    // epilogue: d = |e|^2 - 2*S ; running (best, idx, amb-bit)
    #pragma unroll
    for (int ni = 0; ni < 4; ++ni) {
      const int e = ebase + 16 * ni + c;
      const float en = enorm[e];
      #pragma unroll
      for (int mi = 0; mi < 2; ++mi)
        #pragma unroll
        for (int r = 0; r < 4; ++r) {
          const unsigned bit = 1u << (mi * 4 + r);
          float old = bd[mi][r];
          float d = en - 2.0f * acc[mi][ni][r];
          bool better = d < old;
          bool nearr  = fabsf(d - old) < MARGIN;
          if (better) { bd[mi][r] = d; bi[mi][r] = e; }
          unsigned nb = better ? (nearr ? bit : 0u)
                               : ((amb & bit) | (nearr ? bit : 0u));
          amb = (amb & ~bit) | nb;
        }
    }
  }

  // butterfly reduce across the 16 lanes of each g-group (same n-set, different e)
  #pragma unroll
  for (int off = 1; off < 16; off <<= 1) {
    unsigned oamb = __shfl_xor(amb, off);
    unsigned namb = 0u;
    #pragma unroll
    for (int mi = 0; mi < 2; ++mi)
      #pragma unroll
      for (int r = 0; r < 4; ++r) {
        const unsigned bit = 1u << (mi * 4 + r);
        float od = __shfl_xor(bd[mi][r], off);
        int   oi = __shfl_xor(bi[mi][r], off);
        bool nearr = fabsf(od - bd[mi][r]) < MARGIN;
        bool ow = (od < bd[mi][r]) || (od == bd[mi][r] && oi < bi[mi][r]);
        unsigned sel = ow ? (oamb & bit) : (amb & bit);
        if (ow) { bd[mi][r] = od; bi[mi][r] = oi; }
        if (nearr) sel |= bit;
        namb |= sel;
      }
    amb = namb;
  }

  __syncthreads();                       // done reading A; reuse LDS
  float* sd = (float*)smem;              // [8][32]
  int*   si = (int*)(smem + 1024);
  int*   sa = (int*)(smem + 2048);
  if (c == 0) {
    #pragma unroll
    for (int mi = 0; mi < 2; ++mi)
      #pragma unroll
      for (int r = 0; r < 4; ++r) {
        int nloc = 16 * mi + 4 * g + r;
        sd[w * 32 + nloc] = bd[mi][r];
        si[w * 32 + nloc] = bi[mi][r];
        sa[w * 32 + nloc] = (int)((amb >> (mi * 4 + r)) & 1u);
      }
  }
  __syncthreads();
  if (t < 64) {
    const int half = t >> 5;             // which n-half (wave group)
    const int rloc = t & 31;
    const int base = half * 128 + rloc;  // waves half*4 .. half*4+3
    float d = sd[base]; int i = si[base]; int a = sa[base];
    #pragma unroll
    for (int j = 1; j < 4; ++j) {
      float od = sd[base + j * 32];
      int   oi = si[base + j * 32];
      int   oa = sa[base + j * 32];
      bool nearr = fabsf(od - d) < MARGIN;
      bool ow = (od < d) || (od == d && oi < i);
      a = (ow ? oa : a) | (nearr ? 1 : 0);
      if (ow) { d = od; i = oi; }
    }
    const int n = n0 + t;
    idx_ws[n]  = i;
    idx_out[n] = (float)i;
    atomicAdd(&counts[i], 1.0f);
    if (a) {                             // ambiguous under split-f16 error bound
      int p = atomicAdd(flag_cnt, 1);
      flag_list[p] = n;
    }
  }
}

// ---------------- K2b: exact fp32 re-argmin for flagged vectors ----------------
__global__ __launch_bounds__(256) void fixup_kernel(
    const float* __restrict__ z, const float* __restrict__ emb,
    const float* __restrict__ enorm, const int* __restrict__ flag_cnt,
    const int* __restrict__ flag_list, int* __restrict__ idx_ws,
    float* __restrict__ idx_out, float* __restrict__ counts) {
  __shared__ float zf[256];
  __shared__ float rd[256];
  __shared__ int   ri[256];
  const int t = threadIdx.x;
  const int cnt = *flag_cnt;
  for (int fi = blockIdx.x; fi < cnt; fi += gridDim.x) {
    const int n = flag_list[fi];
    const int b = n >> 12, hw = n & 4095;
    __syncthreads();
    zf[t] = z[((size_t)b << 20) + ((size_t)t << 12) + hw];
    __syncthreads();
    float bdv = 3.0e38f; int biv = 0;
    #pragma unroll 1
    for (int rep = 0; rep < 4; ++rep) {
      const int e = rep * 256 + t;       // e ascending per thread
      const float4* er = (const float4*)(emb + ((size_t)e << 8));
      const float4* zr = (const float4*)zf;
      float d0 = 0.f, d1 = 0.f, d2 = 0.f, d3 = 0.f;  // 4 chains -> no serial stall
      #pragma unroll 8
      for (int k4 = 0; k4 < 64; ++k4) {
        float4 ev = er[k4];
        float4 zv = zr[k4];              // same addr all lanes -> LDS broadcast
        d0 = fmaf(ev.x, zv.x, d0);
        d1 = fmaf(ev.y, zv.y, d1);
        d2 = fmaf(ev.z, zv.z, d2);
        d3 = fmaf(ev.w, zv.w, d3);
      }
      float d = enorm[e] - 2.0f * ((d0 + d1) + (d2 + d3));
      if (d < bdv) { bdv = d; biv = e; }
    }
    rd[t] = bdv; ri[t] = biv;
    __syncthreads();
    for (int s = 128; s > 0; s >>= 1) {
      if (t < s) {
        float od = rd[t + s]; int oi = ri[t + s];
        if (od < rd[t] || (od == rd[t] && oi < ri[t])) { rd[t] = od; ri[t] = oi; }
      }
      __syncthreads();
    }
    if (t == 0) {
      const int nw  = ri[0];
      const int old = idx_ws[n];
      if (nw != old) {
        atomicAdd(&counts[old], -1.0f);
        atomicAdd(&counts[nw],  1.0f);
        idx_ws[n]  = nw;
        idx_out[n] = (float)nw;
      }
    }
    __syncthreads();
  }
}

// ---------------- K3: fused z_q gather + loss + emb_sum histogram ----------------
__global__ __launch_bounds__(256) void fused_scatter_kernel(
    const float* __restrict__ z, const float* __restrict__ emb,
    const int* __restrict__ idx_ws, float* __restrict__ zq_out,
    float* __restrict__ loss_acc, float* __restrict__ emb_sum) {
  __shared__ float hist[NE];
  int t = threadIdx.x;
  #pragma unroll
  for (int i = t; i < NE; i += 256) hist[i] = 0.0f;
  __syncthreads();

  int c     = blockIdx.x & 255;
  int chunk = blockIdx.x >> 8;   // 0..7
  int base  = chunk << 14;       // 16384 vectors per chunk

  float lsum = 0.0f;
  const int4* idx4 = (const int4*)idx_ws;
  for (int i4 = t; i4 < 4096; i4 += 256) {
    int n0 = base + (i4 << 2);
    int b  = n0 >> 12;
    int hw = n0 & 4095;
    size_t off = (((size_t)(b << 8) + c) << 12) + hw;
    float4 v = *(const float4*)(z + off);
    int4 id = idx4[n0 >> 2];
    float4 q;
    q.x = emb[((size_t)id.x << 8) + c];
    q.y = emb[((size_t)id.y << 8) + c];
    q.z = emb[((size_t)id.z << 8) + c];
    q.w = emb[((size_t)id.w << 8) + c];
    *(float4*)(zq_out + off) = q;
    float dx = q.x - v.x, dy = q.y - v.y, dz = q.z - v.z, dw = q.w - v.w;
    lsum += dx * dx + dy * dy + dz * dz + dw * dw;
    atomicAdd(&hist[id.x], v.x);
    atomicAdd(&hist[id.y], v.y);
    atomicAdd(&hist[id.z], v.z);
    atomicAdd(&hist[id.w], v.w);
  }
  __syncthreads();

  for (int e = t; e < NE; e += 256)
    atomicAdd(&emb_sum[(e << 8) + c], hist[e]);

  __shared__ float red[256];
  red[t] = lsum;
  __syncthreads();
  for (int s = 128; s > 0; s >>= 1) {
    if (t < s) red[t] += red[t + s];
    __syncthreads();
  }
  if (t == 0) atomicAdd(loss_acc, red[0]);
}

// ---------------- K5: new_cluster_size + n reduction + loss finalize ----------------
__global__ __launch_bounds__(1024) void ema_cs_kernel(
    const float* __restrict__ cs, const float* __restrict__ counts,
    float* __restrict__ out_ncs, float* __restrict__ n_ws,
    const float* __restrict__ loss_acc, float* __restrict__ loss_out) {
  int e = threadIdx.x;
  float ncs = cs[e] * DECAY + ONE_MINUS_DECAY * counts[e];
  out_ncs[e] = ncs;
  __shared__ float red[1024];
  red[e] = ncs;
  __syncthreads();
  for (int s = 512; s > 0; s >>= 1) {
    if (e < s) red[e] += red[e + s];
    __syncthreads();
  }
  if (e == 0) {
    n_ws[0] = red[0];
    loss_out[0] = loss_acc[0] * 2.0f / (float)ZQ_ELEMS;  // (1+beta)*mse
  }
}

// ---------------- K6: new_embedding_avg + new_embedding ----------------
__global__ __launch_bounds__(256) void ema_emb_kernel(
    const float* __restrict__ eavg, const float* __restrict__ emb_sum,
    const float* __restrict__ ncs, const float* __restrict__ n_ws,
    float* __restrict__ out_eavg, float* __restrict__ out_emb) {
  int i = blockIdx.x * 256 + threadIdx.x;  // 262144 elems
  int e = i >> 8;
  float ea = eavg[i] * DECAY + ONE_MINUS_DECAY * emb_sum[i];
  out_eavg[i] = ea;
  float nv   = n_ws[0];
  float ncse = ncs[e];
  float sm   = (ncse + EPSV) / (nv + (float)NE * EPSV) * nv;
  out_emb[i] = ea / sm;
}

extern "C" void kernel_launch(void* const* d_in, const int* in_sizes, int n_in,
                              void* d_out, int out_size, void* d_ws, size_t ws_size,
                              hipStream_t stream) {
  const float* z    = (const float*)d_in[0];  // [32,256,64,64]
  const float* emb  = (const float*)d_in[1];  // [1024,256]
  const float* eavg = (const float*)d_in[2];  // [1024,256]
  const float* cs   = (const float*)d_in[3];  // [1024]

  float* out = (float*)d_out;
  float* out_zq   = out;                         // 33554432
  float* out_loss = out + 33554432;              // 1
  float* out_idx  = out + 33554433;              // 131072
  float* out_emb  = out + 33685505;              // 262144
  float* out_eavg = out + 33947649;              // 262144
  float* out_ncs  = out + 34209793;              // 1024

  // workspace layout (floats)
  float* ws       = (float*)d_ws;
  int*   idx_ws   = (int*)ws;                    // 131072 ints
  float* emb_sum  = ws + 131072;                 // 262144
  float* counts   = ws + 393216;                 // 1024
  float* loss_acc = ws + 394240;                 // 1
  float* n_ws     = ws + 394241;                 // 1
  float* enorm    = ws + 394244;                 // 1024

  // scratch in the (not yet written) z_q output region:
  // embH/embL f16 splits (262144 floats) + flag counter + flag list.
  _Float16* embH  = (_Float16*)out_zq;                   // 262144 halfs
  _Float16* embL  = (_Float16*)(out_zq + 131072);        // 262144 halfs
  int* flag_cnt   = (int*)(out_zq + 262144);             // 1
  int* flag_list  = (int*)(out_zq + 262145);             // up to 131072

  // zero emb_sum + counts + loss + n, and the flag counter
  hipMemsetAsync(ws + 131072, 0, (size_t)263170 * sizeof(float), stream);
  hipMemsetAsync(out_zq + 262144, 0, sizeof(int), stream);

  prep_half_kernel<<<256, 256, 0, stream>>>(emb, embH, embL);
  enorm_kernel<<<NE / 4, 256, 0, stream>>>(emb, enorm);
  argmin_kernel<<<NVEC / 64, 512, 0, stream>>>(z, embH, embL, enorm, idx_ws,
                                               out_idx, counts, flag_cnt, flag_list);
  fixup_kernel<<<1024, 256, 0, stream>>>(z, emb, enorm, flag_cnt, flag_list,
                                         idx_ws, out_idx, counts);
  fused_scatter_kernel<<<2048, 256, 0, stream>>>(z, emb, idx_ws, out_zq, loss_acc, emb_sum);
  ema_cs_kernel<<<1, 1024, 0, stream>>>(cs, counts, out_ncs, n_ws, loss_acc, out_loss);
  ema_emb_kernel<<<262144 / 256, 256, 0, stream>>>(eavg, emb_sum, out_ncs, n_ws, out_eavg, out_emb);
}

// Round 7
// 1196.355 us; speedup vs baseline: 1.3342x; 1.3342x over previous
//
#include <hip/hip_runtime.h>

// Problem constants
#define BATCH 32
#define CDIM 256
#define HW 4096            // 64*64
#define NVEC 131072        // BATCH*HW
#define NE 1024
#define DECAY 0.99f
#define ONE_MINUS_DECAY 0.01f
#define EPSV 1e-5f
#define ZQ_ELEMS 33554432  // BATCH*CDIM*HW
#define MARGIN 0.02f       // f16-split worst-case distance error ~0.003; 6x safety

typedef _Float16 half8 __attribute__((ext_vector_type(8)));
typedef _Float16 half4 __attribute__((ext_vector_type(4)));
typedef float    f32x4 __attribute__((ext_vector_type(4)));

// ---------------- K0: emb fp32 -> f16 hi/lo split arrays [1024,256] ----------------
__global__ __launch_bounds__(256) void prep_half_kernel(
    const float* __restrict__ emb, _Float16* __restrict__ embH,
    _Float16* __restrict__ embL) {
  int i = blockIdx.x * 256 + threadIdx.x;   // 65536 float4 chunks
  float4 v = ((const float4*)emb)[i];
  float x[4] = {v.x, v.y, v.z, v.w};
  half4 hv, lv;
  #pragma unroll
  for (int j = 0; j < 4; ++j) {
    _Float16 h = (_Float16)x[j];
    hv[j] = h;
    lv[j] = (_Float16)(x[j] - (float)h);
  }
  *(half4*)(embH + 4 * (size_t)i) = hv;
  *(half4*)(embL + 4 * (size_t)i) = lv;
}

// ---------------- K1: embedding row squared norms (fp32, exact) ----------------
__global__ __launch_bounds__(256) void enorm_kernel(
    const float* __restrict__ emb, float* __restrict__ enorm) {
  int gid  = blockIdx.x * 256 + threadIdx.x;
  int e    = gid >> 6;
  int lane = threadIdx.x & 63;
  const float4* row = (const float4*)(emb + ((size_t)e << 8));
  float4 v = row[lane];
  float s = v.x * v.x + v.y * v.y + v.z * v.z + v.w * v.w;
  #pragma unroll
  for (int off = 32; off > 0; off >>= 1) s += __shfl_down(s, off);
  if (lane == 0) enorm[e] = s;
}

// ---------------- K2: MFMA argmin — 3-term f16 split GEMM + argmin epilogue ----------
// Block: 64 n-rows, 512 thr = 8 waves (2 n-halves x 4 e-strips), wave tile
// 32n x 64e, 4 e-passes (E=1024). A (z hi/lo f16) staged once in LDS,
// XOR-swizzled; B (embH/embL) read from global (L2-resident, 1MB) directly
// into fragments -> K-loop has NO barriers.
// LAUNCH BOUNDS LESSON (r5/r6 data): the 2nd arg is BLOCKS/CU (CUDA
// semantics): (256,1)->VGPR 256, (512,4)->VGPR 64+spills. For 4 waves/EU
// with 8-wave blocks we need 2 blocks/CU -> (512,2) -> VGPR budget 128.
// Live state ~97 regs fits -> no spills, 16 waves/CU (50% occupancy,
// LDS-exact: 2 x 64KB of 160KB).
__global__ __launch_bounds__(512, 2) void argmin_kernel(
    const float* __restrict__ z, const _Float16* __restrict__ embH,
    const _Float16* __restrict__ embL, const float* __restrict__ enorm,
    int* __restrict__ idx_ws, float* __restrict__ idx_out,
    float* __restrict__ counts, int* __restrict__ flag_cnt,
    int* __restrict__ flag_list) {
  // zh [64][256] f16 (32KB) + zl (32KB); 16B slots XOR-swizzled by (row&31)
  __shared__ char smem[65536];

  const int t = threadIdx.x;
  const int w = t >> 6;        // wave 0..7
  const int l = t & 63;
  const int g = l >> 4;        // 0..3: k-group (A/B), row-group (D)
  const int c = l & 15;        // 0..15: A row / B,D col
  const int wn = w >> 2;       // n-half: rows 32*wn .. 32*wn+31
  const int we = w & 3;        // e-strip

  const int n0  = blockIdx.x * 64;
  const int b   = n0 >> 12;
  const int hw0 = n0 & 4095;
  const float* zb = z + ((size_t)b << 20) + hw0;

  // ---- stage A once: z[64n][256k] -> f16 hi/lo, swizzled slots ----
  {
    const int n  = t & 63;
    const int kg = t >> 6;     // 0..7
    char* zhp = smem;
    char* zlp = smem + 32768;
    #pragma unroll
    for (int it = 0; it < 4; ++it) {
      const int k0 = it * 64 + kg * 8;
      half8 hv, lv;
      #pragma unroll
      for (int j = 0; j < 8; ++j) {
        float x = zb[(size_t)(k0 + j) * HW + n];   // coalesced across lanes (n)
        _Float16 h = (_Float16)x;
        hv[j] = h;
        lv[j] = (_Float16)(x - (float)h);
      }
      const int slot = ((k0 >> 3) ^ (n & 31)) & 31;
      const int byte = n * 512 + slot * 16;
      *(half8*)(zhp + byte) = hv;
      *(half8*)(zlp + byte) = lv;
    }
  }
  __syncthreads();

  // per-lane running best over the 8 n-rows this lane owns:
  // n = 32*wn + 16*mi + 4*g + r
  // amb: bit (mi*4+r) set <=> some e within MARGIN of current best for that row
  float bd[2][4];
  int   bi[2][4];
  unsigned amb = 0u;
  #pragma unroll
  for (int mi = 0; mi < 2; ++mi)
    #pragma unroll
    for (int r = 0; r < 4; ++r) { bd[mi][r] = 3.0e38f; bi[mi][r] = 0; }

  int arow[2], axor[2];
  #pragma unroll
  for (int mi = 0; mi < 2; ++mi) {
    int rowm = 32 * wn + 16 * mi + c;  // A row this lane supplies
    arow[mi] = rowm * 512;
    axor[mi] = rowm & 31;
  }

  const char* bhp = (const char*)embH;
  const char* blp = (const char*)embL;

  #pragma unroll 1
  for (int et = 0; et < 4; ++et) {
    const int ebase = et * 256 + we * 64;
    f32x4 acc[2][4];
    #pragma unroll
    for (int mi = 0; mi < 2; ++mi)
      #pragma unroll
      for (int ni = 0; ni < 4; ++ni) {
        f32x4 zr = {0.0f, 0.0f, 0.0f, 0.0f};
        acc[mi][ni] = zr;
      }

    int boff[4];
    #pragma unroll
    for (int ni = 0; ni < 4; ++ni) {
      int eg = ebase + 16 * ni + c;              // B col (e) this lane supplies
      boff[ni] = eg * 512 + g * 16;
    }

    // barrier-free K loop; B-frags in 2 ni-halves to cap register pressure
    #pragma unroll
    for (int kc = 0; kc < 256; kc += 32) {
      half8 ah[2], al[2];
      const int kslot = (kc >> 3) + g;
      #pragma unroll
      for (int mi = 0; mi < 2; ++mi) {
        int byte = arow[mi] + (((kslot ^ axor[mi]) & 31) << 4);
        ah[mi] = *(const half8*)(smem + byte);
        al[mi] = *(const half8*)(smem + 32768 + byte);
      }
      #pragma unroll
      for (int nh = 0; nh < 2; ++nh) {
        half8 bh0, bl0, bh1, bl1;
        {
          int o0 = boff[2 * nh]     + kc * 2;
          int o1 = boff[2 * nh + 1] + kc * 2;
          bh0 = *(const half8*)(bhp + o0);
          bl0 = *(const half8*)(blp + o0);
          bh1 = *(const half8*)(bhp + o1);
          bl1 = *(const half8*)(blp + o1);
        }
        #pragma unroll
        for (int mi = 0; mi < 2; ++mi) {
          acc[mi][2*nh]   = __builtin_amdgcn_mfma_f32_16x16x32_f16(ah[mi], bh0, acc[mi][2*nh],   0, 0, 0);
          acc[mi][2*nh]   = __builtin_amdgcn_mfma_f32_16x16x32_f16(ah[mi], bl0, acc[mi][2*nh],   0, 0, 0);
          acc[mi][2*nh]   = __builtin_amdgcn_mfma_f32_16x16x32_f16(al[mi], bh0, acc[mi][2*nh],   0, 0, 0);
          acc[mi][2*nh+1] = __builtin_amdgcn_mfma_f32_16x16x32_f16(ah[mi], bh1, acc[mi][2*nh+1], 0, 0, 0);
          acc[mi][2*nh+1] = __builtin_amdgcn_mfma_f32_16x16x32_f16(ah[mi], bl1, acc[mi][2*nh+1], 0, 0, 0);
          acc[mi][2*nh+1] = __builtin_amdgcn_mfma_f32_16x16x32_f16(al[mi], bh1, acc[mi][2*nh+1], 0, 0, 0);
        }
      }
    }

    // epilogue: d = |e|^2 - 2*S ; running (best, idx, amb-bit)
    #pragma unroll
    for (int ni = 0; ni < 4; ++ni) {
      const int e = ebase + 16 * ni + c;
      const float en = enorm[e];
      #pragma unroll
      for (int mi = 0; mi < 2; ++mi)
        #pragma unroll
        for (int r = 0; r < 4; ++r) {
          const unsigned bit = 1u << (mi * 4 + r);
          float old = bd[mi][r];
          float d = en - 2.0f * acc[mi][ni][r];
          bool better = d < old;
          bool nearr  = fabsf(d - old) < MARGIN;
          if (better) { bd[mi][r] = d; bi[mi][r] = e; }
          unsigned nb = better ? (nearr ? bit : 0u)
                               : ((amb & bit) | (nearr ? bit : 0u));
          amb = (amb & ~bit) | nb;
        }
    }
  }

  // butterfly reduce across the 16 lanes of each g-group (same n-set, different e)
  #pragma unroll
  for (int off = 1; off < 16; off <<= 1) {
    unsigned oamb = __shfl_xor(amb, off);
    unsigned namb = 0u;
    #pragma unroll
    for (int mi = 0; mi < 2; ++mi)
      #pragma unroll
      for (int r = 0; r < 4; ++r) {
        const unsigned bit = 1u << (mi * 4 + r);
        float od = __shfl_xor(bd[mi][r], off);
        int   oi = __shfl_xor(bi[mi][r], off);
        bool nearr = fabsf(od - bd[mi][r]) < MARGIN;
        bool ow = (od < bd[mi][r]) || (od == bd[mi][r] && oi < bi[mi][r]);
        unsigned sel = ow ? (oamb & bit) : (amb & bit);
        if (ow) { bd[mi][r] = od; bi[mi][r] = oi; }
        if (nearr) sel |= bit;
        namb |= sel;
      }
    amb = namb;
  }

  __syncthreads();                       // done reading A; reuse LDS
  float* sd = (float*)smem;              // [8][32]
  int*   si = (int*)(smem + 1024);
  int*   sa = (int*)(smem + 2048);
  if (c == 0) {
    #pragma unroll
    for (int mi = 0; mi < 2; ++mi)
      #pragma unroll
      for (int r = 0; r < 4; ++r) {
        int nloc = 16 * mi + 4 * g + r;
        sd[w * 32 + nloc] = bd[mi][r];
        si[w * 32 + nloc] = bi[mi][r];
        sa[w * 32 + nloc] = (int)((amb >> (mi * 4 + r)) & 1u);
      }
  }
  __syncthreads();
  if (t < 64) {
    const int half = t >> 5;             // which n-half (wave group)
    const int rloc = t & 31;
    const int base = half * 128 + rloc;  // waves half*4 .. half*4+3
    float d = sd[base]; int i = si[base]; int a = sa[base];
    #pragma unroll
    for (int j = 1; j < 4; ++j) {
      float od = sd[base + j * 32];
      int   oi = si[base + j * 32];
      int   oa = sa[base + j * 32];
      bool nearr = fabsf(od - d) < MARGIN;
      bool ow = (od < d) || (od == d && oi < i);
      a = (ow ? oa : a) | (nearr ? 1 : 0);
      if (ow) { d = od; i = oi; }
    }
    const int n = n0 + t;
    idx_ws[n]  = i;
    idx_out[n] = (float)i;
    atomicAdd(&counts[i], 1.0f);
    if (a) {                             // ambiguous under split-f16 error bound
      int p = atomicAdd(flag_cnt, 1);
      flag_list[p] = n;
    }
  }
}

// ---------------- K2b: exact fp32 re-argmin for flagged vectors ----------------
__global__ __launch_bounds__(256) void fixup_kernel(
    const float* __restrict__ z, const float* __restrict__ emb,
    const float* __restrict__ enorm, const int* __restrict__ flag_cnt,
    const int* __restrict__ flag_list, int* __restrict__ idx_ws,
    float* __restrict__ idx_out, float* __restrict__ counts) {
  __shared__ float zf[256];
  __shared__ float rd[256];
  __shared__ int   ri[256];
  const int t = threadIdx.x;
  const int cnt = *flag_cnt;
  for (int fi = blockIdx.x; fi < cnt; fi += gridDim.x) {
    const int n = flag_list[fi];
    const int b = n >> 12, hw = n & 4095;
    __syncthreads();
    zf[t] = z[((size_t)b << 20) + ((size_t)t << 12) + hw];
    __syncthreads();
    float bdv = 3.0e38f; int biv = 0;
    #pragma unroll 1
    for (int rep = 0; rep < 4; ++rep) {
      const int e = rep * 256 + t;       // e ascending per thread
      const float4* er = (const float4*)(emb + ((size_t)e << 8));
      const float4* zr = (const float4*)zf;
      float d0 = 0.f, d1 = 0.f, d2 = 0.f, d3 = 0.f;  // 4 chains -> no serial stall
      #pragma unroll 8
      for (int k4 = 0; k4 < 64; ++k4) {
        float4 ev = er[k4];
        float4 zv = zr[k4];              // same addr all lanes -> LDS broadcast
        d0 = fmaf(ev.x, zv.x, d0);
        d1 = fmaf(ev.y, zv.y, d1);
        d2 = fmaf(ev.z, zv.z, d2);
        d3 = fmaf(ev.w, zv.w, d3);
      }
      float d = enorm[e] - 2.0f * ((d0 + d1) + (d2 + d3));
      if (d < bdv) { bdv = d; biv = e; }
    }
    rd[t] = bdv; ri[t] = biv;
    __syncthreads();
    for (int s = 128; s > 0; s >>= 1) {
      if (t < s) {
        float od = rd[t + s]; int oi = ri[t + s];
        if (od < rd[t] || (od == rd[t] && oi < ri[t])) { rd[t] = od; ri[t] = oi; }
      }
      __syncthreads();
    }
    if (t == 0) {
      const int nw  = ri[0];
      const int old = idx_ws[n];
      if (nw != old) {
        atomicAdd(&counts[old], -1.0f);
        atomicAdd(&counts[nw],  1.0f);
        idx_ws[n]  = nw;
        idx_out[n] = (float)nw;
      }
    }
    __syncthreads();
  }
}

// ---------------- K3: fused z_q gather + loss + emb_sum histogram ----------------
__global__ __launch_bounds__(256) void fused_scatter_kernel(
    const float* __restrict__ z, const float* __restrict__ emb,
    const int* __restrict__ idx_ws, float* __restrict__ zq_out,
    float* __restrict__ loss_acc, float* __restrict__ emb_sum) {
  __shared__ float hist[NE];
  int t = threadIdx.x;
  #pragma unroll
  for (int i = t; i < NE; i += 256) hist[i] = 0.0f;
  __syncthreads();

  int c     = blockIdx.x & 255;
  int chunk = blockIdx.x >> 8;   // 0..7
  int base  = chunk << 14;       // 16384 vectors per chunk

  float lsum = 0.0f;
  const int4* idx4 = (const int4*)idx_ws;
  for (int i4 = t; i4 < 4096; i4 += 256) {
    int n0 = base + (i4 << 2);
    int b  = n0 >> 12;
    int hw = n0 & 4095;
    size_t off = (((size_t)(b << 8) + c) << 12) + hw;
    float4 v = *(const float4*)(z + off);
    int4 id = idx4[n0 >> 2];
    float4 q;
    q.x = emb[((size_t)id.x << 8) + c];
    q.y = emb[((size_t)id.y << 8) + c];
    q.z = emb[((size_t)id.z << 8) + c];
    q.w = emb[((size_t)id.w << 8) + c];
    *(float4*)(zq_out + off) = q;
    float dx = q.x - v.x, dy = q.y - v.y, dz = q.z - v.z, dw = q.w - v.w;
    lsum += dx * dx + dy * dy + dz * dz + dw * dw;
    atomicAdd(&hist[id.x], v.x);
    atomicAdd(&hist[id.y], v.y);
    atomicAdd(&hist[id.z], v.z);
    atomicAdd(&hist[id.w], v.w);
  }
  __syncthreads();

  for (int e = t; e < NE; e += 256)
    atomicAdd(&emb_sum[(e << 8) + c], hist[e]);

  __shared__ float red[256];
  red[t] = lsum;
  __syncthreads();
  for (int s = 128; s > 0; s >>= 1) {
    if (t < s) red[t] += red[t + s];
    __syncthreads();
  }
  if (t == 0) atomicAdd(loss_acc, red[0]);
}

// ---------------- K5: new_cluster_size + n reduction + loss finalize ----------------
__global__ __launch_bounds__(1024) void ema_cs_kernel(
    const float* __restrict__ cs, const float* __restrict__ counts,
    float* __restrict__ out_ncs, float* __restrict__ n_ws,
    const float* __restrict__ loss_acc, float* __restrict__ loss_out) {
  int e = threadIdx.x;
  float ncs = cs[e] * DECAY + ONE_MINUS_DECAY * counts[e];
  out_ncs[e] = ncs;
  __shared__ float red[1024];
  red[e] = ncs;
  __syncthreads();
  for (int s = 512; s > 0; s >>= 1) {
    if (e < s) red[e] += red[e + s];
    __syncthreads();
  }
  if (e == 0) {
    n_ws[0] = red[0];
    loss_out[0] = loss_acc[0] * 2.0f / (float)ZQ_ELEMS;  // (1+beta)*mse
  }
}

// ---------------- K6: new_embedding_avg + new_embedding ----------------
__global__ __launch_bounds__(256) void ema_emb_kernel(
    const float* __restrict__ eavg, const float* __restrict__ emb_sum,
    const float* __restrict__ ncs, const float* __restrict__ n_ws,
    float* __restrict__ out_eavg, float* __restrict__ out_emb) {
  int i = blockIdx.x * 256 + threadIdx.x;  // 262144 elems
  int e = i >> 8;
  float ea = eavg[i] * DECAY + ONE_MINUS_DECAY * emb_sum[i];
  out_eavg[i] = ea;
  float nv   = n_ws[0];
  float ncse = ncs[e];
  float sm   = (ncse + EPSV) / (nv + (float)NE * EPSV) * nv;
  out_emb[i] = ea / sm;
}

extern "C" void kernel_launch(void* const* d_in, const int* in_sizes, int n_in,
                              void* d_out, int out_size, void* d_ws, size_t ws_size,
                              hipStream_t stream) {
  const float* z    = (const float*)d_in[0];  // [32,256,64,64]
  const float* emb  = (const float*)d_in[1];  // [1024,256]
  const float* eavg = (const float*)d_in[2];  // [1024,256]
  const float* cs   = (const float*)d_in[3];  // [1024]

  float* out = (float*)d_out;
  float* out_zq   = out;                         // 33554432
  float* out_loss = out + 33554432;              // 1
  float* out_idx  = out + 33554433;              // 131072
  float* out_emb  = out + 33685505;              // 262144
  float* out_eavg = out + 33947649;              // 262144
  float* out_ncs  = out + 34209793;              // 1024

  // workspace layout (floats)
  float* ws       = (float*)d_ws;
  int*   idx_ws   = (int*)ws;                    // 131072 ints
  float* emb_sum  = ws + 131072;                 // 262144
  float* counts   = ws + 393216;                 // 1024
  float* loss_acc = ws + 394240;                 // 1
  float* n_ws     = ws + 394241;                 // 1
  float* enorm    = ws + 394244;                 // 1024

  // scratch in the (not yet written) z_q output region:
  // embH/embL f16 splits (262144 floats) + flag counter + flag list.
  _Float16* embH  = (_Float16*)out_zq;                   // 262144 halfs
  _Float16* embL  = (_Float16*)(out_zq + 131072);        // 262144 halfs
  int* flag_cnt   = (int*)(out_zq + 262144);             // 1
  int* flag_list  = (int*)(out_zq + 262145);             // up to 131072

  // zero emb_sum + counts + loss + n, and the flag counter
  hipMemsetAsync(ws + 131072, 0, (size_t)263170 * sizeof(float), stream);
  hipMemsetAsync(out_zq + 262144, 0, sizeof(int), stream);

  prep_half_kernel<<<256, 256, 0, stream>>>(emb, embH, embL);
  enorm_kernel<<<NE / 4, 256, 0, stream>>>(emb, enorm);
  argmin_kernel<<<NVEC / 64, 512, 0, stream>>>(z, embH, embL, enorm, idx_ws,
                                               out_idx, counts, flag_cnt, flag_list);
  fixup_kernel<<<1024, 256, 0, stream>>>(z, emb, enorm, flag_cnt, flag_list,
                                         idx_ws, out_idx, counts);
  fused_scatter_kernel<<<2048, 256, 0, stream>>>(z, emb, idx_ws, out_zq, loss_acc, emb_sum);
  ema_cs_kernel<<<1, 1024, 0, stream>>>(cs, counts, out_ncs, n_ws, loss_acc, out_loss);
  ema_emb_kernel<<<262144 / 256, 256, 0, stream>>>(eavg, emb_sum, out_ncs, n_ws, out_eavg, out_emb);
}

// Round 8
// 931.855 us; speedup vs baseline: 1.7129x; 1.2838x over previous
//
#include <hip/hip_runtime.h>

// Problem constants
#define BATCH 32
#define CDIM 256
#define HW 4096            // 64*64
#define NVEC 131072        // BATCH*HW
#define NE 1024
#define DECAY 0.99f
#define ONE_MINUS_DECAY 0.01f
#define EPSV 1e-5f
#define ZQ_ELEMS 33554432  // BATCH*CDIM*HW
#define MARGIN 0.02f       // f16-split worst-case distance error ~0.003; 6x safety

typedef _Float16 half8 __attribute__((ext_vector_type(8)));
typedef _Float16 half4 __attribute__((ext_vector_type(4)));
typedef float    f32x4 __attribute__((ext_vector_type(4)));

// ---------------- K0: emb fp32 -> f16 hi/lo split arrays [1024,256] ----------------
__global__ __launch_bounds__(256) void prep_half_kernel(
    const float* __restrict__ emb, _Float16* __restrict__ embH,
    _Float16* __restrict__ embL) {
  int i = blockIdx.x * 256 + threadIdx.x;   // 65536 float4 chunks
  float4 v = ((const float4*)emb)[i];
  float x[4] = {v.x, v.y, v.z, v.w};
  half4 hv, lv;
  #pragma unroll
  for (int j = 0; j < 4; ++j) {
    _Float16 h = (_Float16)x[j];
    hv[j] = h;
    lv[j] = (_Float16)(x[j] - (float)h);
  }
  *(half4*)(embH + 4 * (size_t)i) = hv;
  *(half4*)(embL + 4 * (size_t)i) = lv;
}

// ---------------- K1: embedding row squared norms (fp32, exact) ----------------
__global__ __launch_bounds__(256) void enorm_kernel(
    const float* __restrict__ emb, float* __restrict__ enorm) {
  int gid  = blockIdx.x * 256 + threadIdx.x;
  int e    = gid >> 6;
  int lane = threadIdx.x & 63;
  const float4* row = (const float4*)(emb + ((size_t)e << 8));
  float4 v = row[lane];
  float s = v.x * v.x + v.y * v.y + v.z * v.z + v.w * v.w;
  #pragma unroll
  for (int off = 32; off > 0; off >>= 1) s += __shfl_down(s, off);
  if (lane == 0) enorm[e] = s;
}

// ---------------- K2: MFMA argmin — 3-term f16 split GEMM + argmin epilogue ----------
// Block: 64 n-rows, 512 thr = 8 waves (2 n-halves x 4 e-strips), wave tile
// 32n x 64e, 4 e-passes (E=1024). A (z hi/lo f16) staged once in LDS,
// XOR-swizzled; B (embH/embL) read from global (L2-resident, 1MB) directly
// into fragments -> K-loop has NO barriers.
// r7 lesson: with FULL kc unroll the scheduler hoists up to 64 in-flight
// B-loads -> liveness >> 128 cap -> 250MB spill traffic. unroll 2 bounds
// the window to 16 loads (~2 kc steps) which still covers ~200cy L2
// latency against 24 MFMA x ~5cy of compute per window.
__global__ __launch_bounds__(512, 2) void argmin_kernel(
    const float* __restrict__ z, const _Float16* __restrict__ embH,
    const _Float16* __restrict__ embL, const float* __restrict__ enorm,
    int* __restrict__ idx_ws, float* __restrict__ idx_out,
    float* __restrict__ counts, int* __restrict__ flag_cnt,
    int* __restrict__ flag_list) {
  // zh [64][256] f16 (32KB) + zl (32KB); 16B slots XOR-swizzled by (row&31)
  __shared__ char smem[65536];

  const int t = threadIdx.x;
  const int w = t >> 6;        // wave 0..7
  const int l = t & 63;
  const int g = l >> 4;        // 0..3: k-group (A/B), row-group (D)
  const int c = l & 15;        // 0..15: A row / B,D col
  const int wn = w >> 2;       // n-half: rows 32*wn .. 32*wn+31
  const int we = w & 3;        // e-strip

  const int n0  = blockIdx.x * 64;
  const int b   = n0 >> 12;
  const int hw0 = n0 & 4095;
  const float* zb = z + ((size_t)b << 20) + hw0;

  // ---- stage A once: z[64n][256k] -> f16 hi/lo, swizzled slots ----
  {
    const int n  = t & 63;
    const int kg = t >> 6;     // 0..7
    char* zhp = smem;
    char* zlp = smem + 32768;
    #pragma unroll
    for (int it = 0; it < 4; ++it) {
      const int k0 = it * 64 + kg * 8;
      half8 hv, lv;
      #pragma unroll
      for (int j = 0; j < 8; ++j) {
        float x = zb[(size_t)(k0 + j) * HW + n];   // coalesced across lanes (n)
        _Float16 h = (_Float16)x;
        hv[j] = h;
        lv[j] = (_Float16)(x - (float)h);
      }
      const int slot = ((k0 >> 3) ^ (n & 31)) & 31;
      const int byte = n * 512 + slot * 16;
      *(half8*)(zhp + byte) = hv;
      *(half8*)(zlp + byte) = lv;
    }
  }
  __syncthreads();

  // per-lane running best over the 8 n-rows this lane owns:
  // n = 32*wn + 16*mi + 4*g + r
  // amb: bit (mi*4+r) set <=> some e within MARGIN of current best for that row
  float bd[2][4];
  int   bi[2][4];
  unsigned amb = 0u;
  #pragma unroll
  for (int mi = 0; mi < 2; ++mi)
    #pragma unroll
    for (int r = 0; r < 4; ++r) { bd[mi][r] = 3.0e38f; bi[mi][r] = 0; }

  int arow[2], axor[2];
  #pragma unroll
  for (int mi = 0; mi < 2; ++mi) {
    int rowm = 32 * wn + 16 * mi + c;  // A row this lane supplies
    arow[mi] = rowm * 512;
    axor[mi] = rowm & 31;
  }

  const char* bhp = (const char*)embH;
  const char* blp = (const char*)embL;

  #pragma unroll 1
  for (int et = 0; et < 4; ++et) {
    const int ebase = et * 256 + we * 64;
    f32x4 acc[2][4];
    #pragma unroll
    for (int mi = 0; mi < 2; ++mi)
      #pragma unroll
      for (int ni = 0; ni < 4; ++ni) {
        f32x4 zr = {0.0f, 0.0f, 0.0f, 0.0f};
        acc[mi][ni] = zr;
      }

    int boff[4];
    #pragma unroll
    for (int ni = 0; ni < 4; ++ni) {
      int eg = ebase + 16 * ni + c;              // B col (e) this lane supplies
      boff[ni] = eg * 512 + g * 16;
    }

    // barrier-free K loop; unroll 2 bounds the scheduler's load window
    #pragma unroll 2
    for (int kc = 0; kc < 256; kc += 32) {
      half8 ah[2], al[2];
      const int kslot = (kc >> 3) + g;
      #pragma unroll
      for (int mi = 0; mi < 2; ++mi) {
        int byte = arow[mi] + (((kslot ^ axor[mi]) & 31) << 4);
        ah[mi] = *(const half8*)(smem + byte);
        al[mi] = *(const half8*)(smem + 32768 + byte);
      }
      #pragma unroll
      for (int nh = 0; nh < 2; ++nh) {
        half8 bh0, bl0, bh1, bl1;
        {
          int o0 = boff[2 * nh]     + kc * 2;
          int o1 = boff[2 * nh + 1] + kc * 2;
          bh0 = *(const half8*)(bhp + o0);
          bl0 = *(const half8*)(blp + o0);
          bh1 = *(const half8*)(bhp + o1);
          bl1 = *(const half8*)(blp + o1);
        }
        #pragma unroll
        for (int mi = 0; mi < 2; ++mi) {
          acc[mi][2*nh]   = __builtin_amdgcn_mfma_f32_16x16x32_f16(ah[mi], bh0, acc[mi][2*nh],   0, 0, 0);
          acc[mi][2*nh]   = __builtin_amdgcn_mfma_f32_16x16x32_f16(ah[mi], bl0, acc[mi][2*nh],   0, 0, 0);
          acc[mi][2*nh]   = __builtin_amdgcn_mfma_f32_16x16x32_f16(al[mi], bh0, acc[mi][2*nh],   0, 0, 0);
          acc[mi][2*nh+1] = __builtin_amdgcn_mfma_f32_16x16x32_f16(ah[mi], bh1, acc[mi][2*nh+1], 0, 0, 0);
          acc[mi][2*nh+1] = __builtin_amdgcn_mfma_f32_16x16x32_f16(ah[mi], bl1, acc[mi][2*nh+1], 0, 0, 0);
          acc[mi][2*nh+1] = __builtin_amdgcn_mfma_f32_16x16x32_f16(al[mi], bh1, acc[mi][2*nh+1], 0, 0, 0);
        }
      }
    }

    // epilogue: d = |e|^2 - 2*S ; running (best, idx, amb-bit)
    #pragma unroll
    for (int ni = 0; ni < 4; ++ni) {
      const int e = ebase + 16 * ni + c;
      const float en = enorm[e];
      #pragma unroll
      for (int mi = 0; mi < 2; ++mi)
        #pragma unroll
        for (int r = 0; r < 4; ++r) {
          const unsigned bit = 1u << (mi * 4 + r);
          float old = bd[mi][r];
          float d = en - 2.0f * acc[mi][ni][r];
          bool better = d < old;
          bool nearr  = fabsf(d - old) < MARGIN;
          if (better) { bd[mi][r] = d; bi[mi][r] = e; }
          unsigned nb = better ? (nearr ? bit : 0u)
                               : ((amb & bit) | (nearr ? bit : 0u));
          amb = (amb & ~bit) | nb;
        }
    }
  }

  // butterfly reduce across the 16 lanes of each g-group (same n-set, different e)
  #pragma unroll
  for (int off = 1; off < 16; off <<= 1) {
    unsigned oamb = __shfl_xor(amb, off);
    unsigned namb = 0u;
    #pragma unroll
    for (int mi = 0; mi < 2; ++mi)
      #pragma unroll
      for (int r = 0; r < 4; ++r) {
        const unsigned bit = 1u << (mi * 4 + r);
        float od = __shfl_xor(bd[mi][r], off);
        int   oi = __shfl_xor(bi[mi][r], off);
        bool nearr = fabsf(od - bd[mi][r]) < MARGIN;
        bool ow = (od < bd[mi][r]) || (od == bd[mi][r] && oi < bi[mi][r]);
        unsigned sel = ow ? (oamb & bit) : (amb & bit);
        if (ow) { bd[mi][r] = od; bi[mi][r] = oi; }
        if (nearr) sel |= bit;
        namb |= sel;
      }
    amb = namb;
  }

  __syncthreads();                       // done reading A; reuse LDS
  float* sd = (float*)smem;              // [8][32]
  int*   si = (int*)(smem + 1024);
  int*   sa = (int*)(smem + 2048);
  if (c == 0) {
    #pragma unroll
    for (int mi = 0; mi < 2; ++mi)
      #pragma unroll
      for (int r = 0; r < 4; ++r) {
        int nloc = 16 * mi + 4 * g + r;
        sd[w * 32 + nloc] = bd[mi][r];
        si[w * 32 + nloc] = bi[mi][r];
        sa[w * 32 + nloc] = (int)((amb >> (mi * 4 + r)) & 1u);
      }
  }
  __syncthreads();
  if (t < 64) {
    const int half = t >> 5;             // which n-half (wave group)
    const int rloc = t & 31;
    const int base = half * 128 + rloc;  // waves half*4 .. half*4+3
    float d = sd[base]; int i = si[base]; int a = sa[base];
    #pragma unroll
    for (int j = 1; j < 4; ++j) {
      float od = sd[base + j * 32];
      int   oi = si[base + j * 32];
      int   oa = sa[base + j * 32];
      bool nearr = fabsf(od - d) < MARGIN;
      bool ow = (od < d) || (od == d && oi < i);
      a = (ow ? oa : a) | (nearr ? 1 : 0);
      if (ow) { d = od; i = oi; }
    }
    const int n = n0 + t;
    idx_ws[n]  = i;
    idx_out[n] = (float)i;
    atomicAdd(&counts[i], 1.0f);
    if (a) {                             // ambiguous under split-f16 error bound
      int p = atomicAdd(flag_cnt, 1);
      flag_list[p] = n;
    }
  }
}

// ---------------- K2b: exact fp32 re-argmin for flagged vectors ----------------
__global__ __launch_bounds__(256) void fixup_kernel(
    const float* __restrict__ z, const float* __restrict__ emb,
    const float* __restrict__ enorm, const int* __restrict__ flag_cnt,
    const int* __restrict__ flag_list, int* __restrict__ idx_ws,
    float* __restrict__ idx_out, float* __restrict__ counts) {
  __shared__ float zf[256];
  __shared__ float rd[256];
  __shared__ int   ri[256];
  const int t = threadIdx.x;
  const int cnt = *flag_cnt;
  for (int fi = blockIdx.x; fi < cnt; fi += gridDim.x) {
    const int n = flag_list[fi];
    const int b = n >> 12, hw = n & 4095;
    __syncthreads();
    zf[t] = z[((size_t)b << 20) + ((size_t)t << 12) + hw];
    __syncthreads();
    float bdv = 3.0e38f; int biv = 0;
    #pragma unroll 1
    for (int rep = 0; rep < 4; ++rep) {
      const int e = rep * 256 + t;       // e ascending per thread
      const float4* er = (const float4*)(emb + ((size_t)e << 8));
      const float4* zr = (const float4*)zf;
      float d0 = 0.f, d1 = 0.f, d2 = 0.f, d3 = 0.f;  // 4 chains -> no serial stall
      #pragma unroll 8
      for (int k4 = 0; k4 < 64; ++k4) {
        float4 ev = er[k4];
        float4 zv = zr[k4];              // same addr all lanes -> LDS broadcast
        d0 = fmaf(ev.x, zv.x, d0);
        d1 = fmaf(ev.y, zv.y, d1);
        d2 = fmaf(ev.z, zv.z, d2);
        d3 = fmaf(ev.w, zv.w, d3);
      }
      float d = enorm[e] - 2.0f * ((d0 + d1) + (d2 + d3));
      if (d < bdv) { bdv = d; biv = e; }
    }
    rd[t] = bdv; ri[t] = biv;
    __syncthreads();
    for (int s = 128; s > 0; s >>= 1) {
      if (t < s) {
        float od = rd[t + s]; int oi = ri[t + s];
        if (od < rd[t] || (od == rd[t] && oi < ri[t])) { rd[t] = od; ri[t] = oi; }
      }
      __syncthreads();
    }
    if (t == 0) {
      const int nw  = ri[0];
      const int old = idx_ws[n];
      if (nw != old) {
        atomicAdd(&counts[old], -1.0f);
        atomicAdd(&counts[nw],  1.0f);
        idx_ws[n]  = nw;
        idx_out[n] = (float)nw;
      }
    }
    __syncthreads();
  }
}

// ---------------- K3: fused z_q gather + loss + emb_sum histogram ----------------
__global__ __launch_bounds__(256) void fused_scatter_kernel(
    const float* __restrict__ z, const float* __restrict__ emb,
    const int* __restrict__ idx_ws, float* __restrict__ zq_out,
    float* __restrict__ loss_acc, float* __restrict__ emb_sum) {
  __shared__ float hist[NE];
  int t = threadIdx.x;
  #pragma unroll
  for (int i = t; i < NE; i += 256) hist[i] = 0.0f;
  __syncthreads();

  int c     = blockIdx.x & 255;
  int chunk = blockIdx.x >> 8;   // 0..7
  int base  = chunk << 14;       // 16384 vectors per chunk

  float lsum = 0.0f;
  const int4* idx4 = (const int4*)idx_ws;
  for (int i4 = t; i4 < 4096; i4 += 256) {
    int n0 = base + (i4 << 2);
    int b  = n0 >> 12;
    int hw = n0 & 4095;
    size_t off = (((size_t)(b << 8) + c) << 12) + hw;
    float4 v = *(const float4*)(z + off);
    int4 id = idx4[n0 >> 2];
    float4 q;
    q.x = emb[((size_t)id.x << 8) + c];
    q.y = emb[((size_t)id.y << 8) + c];
    q.z = emb[((size_t)id.z << 8) + c];
    q.w = emb[((size_t)id.w << 8) + c];
    *(float4*)(zq_out + off) = q;
    float dx = q.x - v.x, dy = q.y - v.y, dz = q.z - v.z, dw = q.w - v.w;
    lsum += dx * dx + dy * dy + dz * dz + dw * dw;
    atomicAdd(&hist[id.x], v.x);
    atomicAdd(&hist[id.y], v.y);
    atomicAdd(&hist[id.z], v.z);
    atomicAdd(&hist[id.w], v.w);
  }
  __syncthreads();

  for (int e = t; e < NE; e += 256)
    atomicAdd(&emb_sum[(e << 8) + c], hist[e]);

  __shared__ float red[256];
  red[t] = lsum;
  __syncthreads();
  for (int s = 128; s > 0; s >>= 1) {
    if (t < s) red[t] += red[t + s];
    __syncthreads();
  }
  if (t == 0) atomicAdd(loss_acc, red[0]);
}

// ---------------- K5: new_cluster_size + n reduction + loss finalize ----------------
__global__ __launch_bounds__(1024) void ema_cs_kernel(
    const float* __restrict__ cs, const float* __restrict__ counts,
    float* __restrict__ out_ncs, float* __restrict__ n_ws,
    const float* __restrict__ loss_acc, float* __restrict__ loss_out) {
  int e = threadIdx.x;
  float ncs = cs[e] * DECAY + ONE_MINUS_DECAY * counts[e];
  out_ncs[e] = ncs;
  __shared__ float red[1024];
  red[e] = ncs;
  __syncthreads();
  for (int s = 512; s > 0; s >>= 1) {
    if (e < s) red[e] += red[e + s];
    __syncthreads();
  }
  if (e == 0) {
    n_ws[0] = red[0];
    loss_out[0] = loss_acc[0] * 2.0f / (float)ZQ_ELEMS;  // (1+beta)*mse
  }
}

// ---------------- K6: new_embedding_avg + new_embedding ----------------
__global__ __launch_bounds__(256) void ema_emb_kernel(
    const float* __restrict__ eavg, const float* __restrict__ emb_sum,
    const float* __restrict__ ncs, const float* __restrict__ n_ws,
    float* __restrict__ out_eavg, float* __restrict__ out_emb) {
  int i = blockIdx.x * 256 + threadIdx.x;  // 262144 elems
  int e = i >> 8;
  float ea = eavg[i] * DECAY + ONE_MINUS_DECAY * emb_sum[i];
  out_eavg[i] = ea;
  float nv   = n_ws[0];
  float ncse = ncs[e];
  float sm   = (ncse + EPSV) / (nv + (float)NE * EPSV) * nv;
  out_emb[i] = ea / sm;
}

extern "C" void kernel_launch(void* const* d_in, const int* in_sizes, int n_in,
                              void* d_out, int out_size, void* d_ws, size_t ws_size,
                              hipStream_t stream) {
  const float* z    = (const float*)d_in[0];  // [32,256,64,64]
  const float* emb  = (const float*)d_in[1];  // [1024,256]
  const float* eavg = (const float*)d_in[2];  // [1024,256]
  const float* cs   = (const float*)d_in[3];  // [1024]

  float* out = (float*)d_out;
  float* out_zq   = out;                         // 33554432
  float* out_loss = out + 33554432;              // 1
  float* out_idx  = out + 33554433;              // 131072
  float* out_emb  = out + 33685505;              // 262144
  float* out_eavg = out + 33947649;              // 262144
  float* out_ncs  = out + 34209793;              // 1024

  // workspace layout (floats)
  float* ws       = (float*)d_ws;
  int*   idx_ws   = (int*)ws;                    // 131072 ints
  float* emb_sum  = ws + 131072;                 // 262144
  float* counts   = ws + 393216;                 // 1024
  float* loss_acc = ws + 394240;                 // 1
  float* n_ws     = ws + 394241;                 // 1
  float* enorm    = ws + 394244;                 // 1024

  // scratch in the (not yet written) z_q output region:
  // embH/embL f16 splits (262144 floats) + flag counter + flag list.
  _Float16* embH  = (_Float16*)out_zq;                   // 262144 halfs
  _Float16* embL  = (_Float16*)(out_zq + 131072);        // 262144 halfs
  int* flag_cnt   = (int*)(out_zq + 262144);             // 1
  int* flag_list  = (int*)(out_zq + 262145);             // up to 131072

  // zero emb_sum + counts + loss + n, and the flag counter
  hipMemsetAsync(ws + 131072, 0, (size_t)263170 * sizeof(float), stream);
  hipMemsetAsync(out_zq + 262144, 0, sizeof(int), stream);

  prep_half_kernel<<<256, 256, 0, stream>>>(emb, embH, embL);
  enorm_kernel<<<NE / 4, 256, 0, stream>>>(emb, enorm);
  argmin_kernel<<<NVEC / 64, 512, 0, stream>>>(z, embH, embL, enorm, idx_ws,
                                               out_idx, counts, flag_cnt, flag_list);
  fixup_kernel<<<1024, 256, 0, stream>>>(z, emb, enorm, flag_cnt, flag_list,
                                         idx_ws, out_idx, counts);
  fused_scatter_kernel<<<2048, 256, 0, stream>>>(z, emb, idx_ws, out_zq, loss_acc, emb_sum);
  ema_cs_kernel<<<1, 1024, 0, stream>>>(cs, counts, out_ncs, n_ws, loss_acc, out_loss);
  ema_emb_kernel<<<262144 / 256, 256, 0, stream>>>(eavg, emb_sum, out_ncs, n_ws, out_eavg, out_emb);
}